// Round 7
// baseline (374.260 us; speedup 1.0000x reference)
//
#include <hip/hip_runtime.h>
#include <math.h>

// Fused ConvTranspose3d(32->64,k5,s2,p2) + sum(C_out) + bias + MaxPool(2) + MaxPool(3)
// x: (16,32,48,48,48) f32, weight: (32,64,5,5,5) f32, bias: (64,) f32
// out: (16,1,15,15,15) f32
//
// y[od] = sum x[id]*cw[kd], od = 2*id-2+kd; final out[j] = max over od in [6j,6j+5]^3 + cb.
// Window row r = 2*li + k - 4 (li = local input idx, k = kernel tap).
// LDS: xt[pixel][16ch f16 pairs, pitch 10 u32], weights cw[125][32ch in 16 u32].
// Inner product: v_dot2_f32_f16 (__builtin_amdgcn_fdot2), f32 accumulate.
//
// ROUND 7: round-5 staging had lane mapping (c2=tid&7, p=tid>>3) -> consecutive
// lanes read different channel planes (442 KB apart) -> 64-way scattered global
// loads -> HBM effective 2 TB/s, staging-bound (682 MB ~ whole 296 us).
// Fix: pixel-major lanes per channel slot (coalesced 17-float runs), pixel
// offsets/validity hoisted out of the slot loop. xt pitch padded 8->10 u32 so
// the now-strided LDS writes are only 4-way bank-conflicted (~free).

#define XS (48*48*48)
#define XP 10  // xt pitch in u32 per pixel (8 data + 2 pad)

typedef __fp16 h2 __attribute__((ext_vector_type(2)));  // matches builtin signatures
union UH { unsigned u; h2 h; };

__device__ __forceinline__ unsigned pk16(float a, float b) {
    UH r; r.h = __builtin_amdgcn_cvt_pkrtz(a, b);  // v_cvt_pkrtz_f16_f32
    return r.u;
}

// ---------------- Kernel 1: fold weights over C_out, pack f16 channels-last ----------------
// ws layout: u32[2000] = [pix 0..124][slot 0..15], slot s holds channels (2s, 2s+1).
// ws[2000] (as float) = summed bias.
__global__ void fold_kernel(const float* __restrict__ w,
                            const float* __restrict__ bias,
                            unsigned* __restrict__ ws) {
    int t = blockIdx.x * blockDim.x + threadIdx.x;
    if (t < 2000) {
        int pix = t >> 4, sc = t & 15;
        const float* p0 = w + (size_t)(2 * sc) * 64 * 125 + pix;
        const float* p1 = p0 + 64 * 125;
        float s0 = 0.f, s1 = 0.f;
        #pragma unroll 8
        for (int o = 0; o < 64; ++o) { s0 += p0[o * 125]; s1 += p1[o * 125]; }
        ws[t] = pk16(s0, s1);
    } else if (t == 2000) {
        float s = 0.f;
        for (int o = 0; o < 64; ++o) s += bias[o];
        ((float*)ws)[2000] = s;
    }
}

// ---------------- Kernel 2: fused conv + maxpool ----------------
// Block = 128 thr = fo(5 final outputs along w) x rd(6 d-window rows) x cg(4 channel quads).
// Per (16ch chunk, d-tap): cache 25 x-pixels AND 25 weight taps (uint2 = 4ch f16)
// in registers, then run 450 dot2 with zero loads in the body.
__global__ __launch_bounds__(128)
void fused_kernel(const float* __restrict__ x,
                  const unsigned* __restrict__ wsrc,
                  float* __restrict__ out) {
    __shared__ unsigned xt[425 * XP];  // [pixel(5*5*17)][pitch 10], 17 KB
    __shared__ unsigned cwS[2000];     // [125][16 u32 = 32ch f16], 8 KB
    __shared__ float red[30];

    const int tid = threadIdx.x;
    int bid = blockIdx.x;
    const int bw = bid % 3;  bid /= 3;
    const int jh = bid % 15; bid /= 15;
    const int jd = bid % 15; const int n = bid / 15;
    const int d0 = 3 * jd - 1, h0 = 3 * jh - 1, w0 = 15 * bw - 1;

    // stage packed weights once (500 x b128)
    for (int e = tid; e < 500; e += 128)
        ((uint4*)cwS)[e] = ((const uint4*)wsrc)[e];

    const int fo = tid / 24;        // 0..4
    const int r  = tid % 24;
    const int rd = r >> 2;          // 0..5
    const int cg = r & 3;           // 0..3 -> channels 4cg..4cg+3 of chunk
    const bool active = tid < 120;

    const int ntd  = (rd & 1) ? 2 : 3;
    const int kd0  = rd & 1;
    const int lid0 = (rd + 4 - kd0) >> 1;

    // Per-thread staging pixels: p = tid + 128k, k = 0..3 (425 total).
    // Hoist (dz,dy,dx) -> global offset + validity out of the slot loop.
    int  goff[4];
    bool gval[4];
    #pragma unroll
    for (int k = 0; k < 4; ++k) {
        int p = tid + 128 * k;
        int dz = p / 85;
        int rm = p - dz * 85;
        int dy = rm / 17;
        int dx = rm - dy * 17;
        int gd = d0 + dz, gh = h0 + dy, gw = w0 + dx;
        gval[k] = (p < 425) &
                  ((unsigned)gd < 48u) & ((unsigned)gh < 48u) & ((unsigned)gw < 48u);
        goff[k] = (gd * 48 + gh) * 48 + gw;
    }

    float acc[36];
    #pragma unroll
    for (int i = 0; i < 36; ++i) acc[i] = 0.f;

    for (int chunk = 0; chunk < 2; ++chunk) {
        __syncthreads();
        // stage 16 channels as f16 pairs, slot-major: lanes sweep pixels
        // within one channel plane -> coalesced global reads.
        {
            const float* xn = x + ((size_t)n * 32 + chunk * 16) * XS;
            #pragma unroll
            for (int s = 0; s < 8; ++s) {
                const float* a0 = xn + (size_t)(2 * s) * XS;
                const float* a1 = a0 + XS;
                #pragma unroll
                for (int k = 0; k < 4; ++k) {
                    int p = tid + 128 * k;
                    if (p < 425) {
                        unsigned v = 0;
                        if (gval[k]) v = pk16(a0[goff[k]], a1[goff[k]]);
                        xt[p * XP + s] = v;
                    }
                }
            }
        }
        __syncthreads();

        if (active) {
            #pragma unroll
            for (int a = 0; a < 3; ++a) {
                if (a < ntd) {
                    const int lid = lid0 - a;
                    const int kd  = kd0 + 2 * a;
                    const unsigned* xb = &xt[(lid * 85 + 3 * fo) * XP + cg * 2];
                    const unsigned* wq = &cwS[kd * 25 * 16 + chunk * 8 + cg * 2];

                    // cache the full 5x5 pixel slab (4 ch = uint2 each)
                    uint2 ibr[5][5];
                    #pragma unroll
                    for (int ih = 0; ih < 5; ++ih)
                        #pragma unroll
                        for (int iw = 0; iw < 5; ++iw)
                            ibr[ih][iw] = *(const uint2*)&xb[(ih * 17 + iw) * XP];

                    // cache the full 5x5 weight tap block for this kd
                    uint2 wbr[5][5];
                    #pragma unroll
                    for (int kh = 0; kh < 5; ++kh)
                        #pragma unroll
                        for (int kw = 0; kw < 5; ++kw)
                            wbr[kh][kw] = *(const uint2*)&wq[(kh * 5 + kw) * 16];

                    // load-free dot2 body: 225 valid tap combos x 2 dot2
                    #pragma unroll
                    for (int kh = 0; kh < 5; ++kh) {
                        #pragma unroll
                        for (int lih = 0; lih < 5; ++lih) {
                            const int rh = 2 * lih + kh - 4;
                            if (rh >= 0 && rh < 6) {
                                #pragma unroll
                                for (int liw = 0; liw < 5; ++liw) {
                                    #pragma unroll
                                    for (int kw = 0; kw < 5; ++kw) {
                                        const int rw = 2 * liw + kw - 4;
                                        if (rw >= 0 && rw < 6) {
                                            UH x0, x1, w0v, w1v;
                                            x0.u = ibr[lih][liw].x;
                                            x1.u = ibr[lih][liw].y;
                                            w0v.u = wbr[kh][kw].x;
                                            w1v.u = wbr[kh][kw].y;
                                            float s = acc[rh * 6 + rw];
                                            s = __builtin_amdgcn_fdot2(x0.h, w0v.h, s, false);
                                            s = __builtin_amdgcn_fdot2(x1.h, w1v.h, s, false);
                                            acc[rh * 6 + rw] = s;
                                        }
                                    }
                                }
                            }
                        }
                    }
                }
            }
        }
    }

    // sum over cg (4 adjacent lanes), then max over the 6x6 slab
    if (active) {
        #pragma unroll
        for (int i = 0; i < 36; ++i) {
            acc[i] += __shfl_xor(acc[i], 1);
            acc[i] += __shfl_xor(acc[i], 2);
        }
        if (cg == 0) {
            float m = -INFINITY;
            #pragma unroll
            for (int i = 0; i < 36; ++i) m = fmaxf(m, acc[i]);
            red[fo * 6 + rd] = m;
        }
    }
    __syncthreads();
    if (tid < 5) {
        float m = -INFINITY;
        #pragma unroll
        for (int k = 0; k < 6; ++k) m = fmaxf(m, red[tid * 6 + k]);
        float cb = ((const float*)wsrc)[2000];
        out[(((size_t)n * 15 + jd) * 15 + jh) * 15 + 5 * bw + tid] = m + cb;
    }
}

extern "C" void kernel_launch(void* const* d_in, const int* in_sizes, int n_in,
                              void* d_out, int out_size, void* d_ws, size_t ws_size,
                              hipStream_t stream) {
    const float* x = (const float*)d_in[0];
    const float* w = (const float*)d_in[1];
    const float* b = (const float*)d_in[2];
    float* out = (float*)d_out;
    unsigned* ws = (unsigned*)d_ws;

    fold_kernel<<<8, 256, 0, stream>>>(w, b, ws);

    // grid: 3 jw-groups x 15 jh x 15 jd x 16 n
    fused_kernel<<<3 * 15 * 15 * 16, 128, 0, stream>>>(x, ws, out);
}

// Round 8
// 311.337 us; speedup vs baseline: 1.2021x; 1.2021x over previous
//
#include <hip/hip_runtime.h>
#include <math.h>

// Fused ConvTranspose3d(32->64,k5,s2,p2) + sum(C_out) + bias + MaxPool(2) + MaxPool(3)
// x: (16,32,48,48,48) f32, weight: (32,64,5,5,5) f32, bias: (64,) f32
// out: (16,1,15,15,15) f32
//
// y[od] = sum x[id]*cw[kd], od = 2*id-2+kd; final out[j] = max over od in [6j,6j+5]^3 + cb.
// Window row r = 2*li + k - 4.
//
// ROUND 8: rounds 5/7 show dur ~= FETCH / achieved_BW (staging-dominated);
// achieved BW tracks cache-lines-in-flight. New structure: block = (n,jd,jh) x
// full w-row (15 outputs). Tile rows are 48 floats = 3 full aligned lines ->
// dense dwordx4 staging (16 lines per wave instruction, ~14 loads in flight
// per thread), 6-wave blocks, 3 blocks/CU (18 waves/CU). Compute body = round-5
// dot2 kernel (best measured). LDS transpose-write aliasing (~8-way) accepted.

#define XS (48*48*48)

typedef __fp16 h2 __attribute__((ext_vector_type(2)));
union UH { unsigned u; h2 h; };

__device__ __forceinline__ unsigned pk16(float a, float b) {
    UH r; r.h = __builtin_amdgcn_cvt_pkrtz(a, b);  // v_cvt_pkrtz_f16_f32
    return r.u;
}

// ---------------- Kernel 1: fold weights over C_out, pack f16 channels-last ----------------
// ws: u32[2000] = [pix 0..124][slot 0..15]; slot s = channels (2s,2s+1). ws[2000]=bias sum.
__global__ void fold_kernel(const float* __restrict__ w,
                            const float* __restrict__ bias,
                            unsigned* __restrict__ ws) {
    int t = blockIdx.x * blockDim.x + threadIdx.x;
    if (t < 2000) {
        int pix = t >> 4, sc = t & 15;
        const float* p0 = w + (size_t)(2 * sc) * 64 * 125 + pix;
        const float* p1 = p0 + 64 * 125;
        float s0 = 0.f, s1 = 0.f;
        #pragma unroll 8
        for (int o = 0; o < 64; ++o) { s0 += p0[o * 125]; s1 += p1[o * 125]; }
        ws[t] = pk16(s0, s1);
    } else if (t == 2000) {
        float s = 0.f;
        for (int o = 0; o < 64; ++o) s += bias[o];
        ((float*)ws)[2000] = s;
    }
}

// ---------------- Kernel 2: fused conv + maxpool, full w-row per block ----------------
// 384 thr = fo(15 outputs, +1 idle slot) x rd(6) x cg(4).
// xt[px = row*50 + (gw+1)][8 u32]: row = dz*5+dy (25 rows), 16 ch f16 pairs.
__global__ __launch_bounds__(384)
void fused_kernel(const float* __restrict__ x,
                  const unsigned* __restrict__ wsrc,
                  float* __restrict__ out) {
    __shared__ unsigned xt[1250 * 8];  // 25 rows x 50 w-slots x 8 u32 = 40 KB
    __shared__ unsigned cwS[2000];     // [125][16 u32 = 32ch f16], 8 KB
    __shared__ float red[90];          // [fo(15)][rd(6)]

    const int tid = threadIdx.x;
    int bid = blockIdx.x;
    const int jh = bid % 15; bid /= 15;
    const int jd = bid % 15; const int n = bid / 15;
    const int d0 = 3 * jd - 1, h0 = 3 * jh - 1;

    // stage packed weights (500 x b128)
    for (int e = tid; e < 500; e += 384)
        ((uint4*)cwS)[e] = ((const uint4*)wsrc)[e];

    // zero the w-pads (px_w = 0 and 49) once; never overwritten
    for (int e = tid; e < 400; e += 384) {
        int row = e >> 4, rem = e & 15;
        int pxw = (rem & 1) ? 49 : 0;
        int sp  = rem >> 1;
        xt[(row * 50 + pxw) * 8 + sp] = 0;
    }

    const int fo = tid / 24;        // 0..15 (15 = idle slot)
    const int r  = tid % 24;
    const int rd = r >> 2;          // 0..5
    const int cg = r & 3;           // channel quad
    const bool active = fo < 15;

    const int ntd  = (rd & 1) ? 2 : 3;
    const int kd0  = rd & 1;
    const int lid0 = (rd + 4 - kd0) >> 1;

    float acc[36];
    #pragma unroll
    for (int i = 0; i < 36; ++i) acc[i] = 0.f;

    for (int chunk = 0; chunk < 2; ++chunk) {
        __syncthreads();  // prior readers of xt done (or pads/weights on iter 0)

        // ---- stage 16 channels: unit u = (row 0..24, sp 0..7, f4 0..11) ----
        // lane's 2 dwordx4 loads are dense 16B runs; a wave covers ~16 full lines.
        for (int u = tid; u < 2400; u += 384) {
            int sp  = u % 8;
            int t2  = u / 8;
            int f4  = t2 % 12;
            int row = t2 / 12;
            int dz = row / 5, dy = row % 5;
            int gd = d0 + dz, gh = h0 + dy;
            unsigned wb = (unsigned)((row * 50 + 4 * f4 + 1) * 8 + sp);
            if (((unsigned)gd < 48u) & ((unsigned)gh < 48u)) {
                const float* a0 = x + ((size_t)(n * 32 + chunk * 16 + 2 * sp)) * XS
                                    + (gd * 48 + gh) * 48 + 4 * f4;
                const float* a1 = a0 + XS;
                float4 q0 = *(const float4*)a0;
                float4 q1 = *(const float4*)a1;
                xt[wb +  0] = pk16(q0.x, q1.x);
                xt[wb +  8] = pk16(q0.y, q1.y);
                xt[wb + 16] = pk16(q0.z, q1.z);
                xt[wb + 24] = pk16(q0.w, q1.w);
            } else {
                xt[wb +  0] = 0; xt[wb +  8] = 0;
                xt[wb + 16] = 0; xt[wb + 24] = 0;
            }
        }
        __syncthreads();

        // ---- compute: round-5 dot2 body ----
        if (active) {
            #pragma unroll
            for (int a = 0; a < 3; ++a) {
                if (a < ntd) {
                    const int lid = lid0 - a;
                    const int kd  = kd0 + 2 * a;
                    const unsigned* wq = &cwS[kd * 400 + chunk * 8 + cg * 2];

                    uint2 ibr[5][5];
                    #pragma unroll
                    for (int ih = 0; ih < 5; ++ih)
                        #pragma unroll
                        for (int iw = 0; iw < 5; ++iw)
                            ibr[ih][iw] = *(const uint2*)
                                &xt[(((lid * 5 + ih) * 50) + 3 * fo + iw) * 8 + cg * 2];

                    #pragma unroll
                    for (int kh = 0; kh < 5; ++kh) {
                        uint2 wbr[5];
                        #pragma unroll
                        for (int kw = 0; kw < 5; ++kw)
                            wbr[kw] = *(const uint2*)&wq[(kh * 5 + kw) * 16];
                        #pragma unroll
                        for (int lih = 0; lih < 5; ++lih) {
                            const int rh = 2 * lih + kh - 4;
                            if (rh >= 0 && rh < 6) {
                                #pragma unroll
                                for (int liw = 0; liw < 5; ++liw) {
                                    #pragma unroll
                                    for (int kw = 0; kw < 5; ++kw) {
                                        const int rw = 2 * liw + kw - 4;
                                        if (rw >= 0 && rw < 6) {
                                            UH x0, x1, w0v, w1v;
                                            x0.u = ibr[lih][liw].x;
                                            x1.u = ibr[lih][liw].y;
                                            w0v.u = wbr[kw].x;
                                            w1v.u = wbr[kw].y;
                                            float s = acc[rh * 6 + rw];
                                            s = __builtin_amdgcn_fdot2(x0.h, w0v.h, s, false);
                                            s = __builtin_amdgcn_fdot2(x1.h, w1v.h, s, false);
                                            acc[rh * 6 + rw] = s;
                                        }
                                    }
                                }
                            }
                        }
                    }
                }
            }
        }
    }

    // sum over cg (4 adjacent lanes), then max over the 6x6 slab
    if (active) {
        #pragma unroll
        for (int i = 0; i < 36; ++i) {
            acc[i] += __shfl_xor(acc[i], 1);
            acc[i] += __shfl_xor(acc[i], 2);
        }
        if (cg == 0) {
            float m = -INFINITY;
            #pragma unroll
            for (int i = 0; i < 36; ++i) m = fmaxf(m, acc[i]);
            red[fo * 6 + rd] = m;
        }
    }
    __syncthreads();
    if (tid < 15) {
        float m = -INFINITY;
        #pragma unroll
        for (int k = 0; k < 6; ++k) m = fmaxf(m, red[tid * 6 + k]);
        float cb = ((const float*)wsrc)[2000];
        out[(((size_t)n * 15 + jd) * 15 + jh) * 15 + tid] = m + cb;
    }
}

extern "C" void kernel_launch(void* const* d_in, const int* in_sizes, int n_in,
                              void* d_out, int out_size, void* d_ws, size_t ws_size,
                              hipStream_t stream) {
    const float* x = (const float*)d_in[0];
    const float* w = (const float*)d_in[1];
    const float* b = (const float*)d_in[2];
    float* out = (float*)d_out;
    unsigned* ws = (unsigned*)d_ws;

    fold_kernel<<<8, 256, 0, stream>>>(w, b, ws);

    // grid: 15 jh x 15 jd x 16 n, one full w-row per block
    fused_kernel<<<15 * 15 * 16, 384, 0, stream>>>(x, ws, out);
}

// Round 9
// 285.494 us; speedup vs baseline: 1.3109x; 1.0905x over previous
//
#include <hip/hip_runtime.h>
#include <math.h>

// Fused ConvTranspose3d(32->64,k5,s2,p2) + sum(C_out) + bias + MaxPool(2) + MaxPool(3)
// x: (16,32,48,48,48) f32, weight: (32,64,5,5,5) f32, bias: (64,) f32
// out: (16,1,15,15,15) f32
//
// y[od] = sum x[id]*cw[kd], od = 2*id-2+kd; final out[j] = max over od in [6j,6j+5]^3 + cb.
// Window row r = 2*li + k - 4.
//
// ROUND 9: best measured = R5 (296us, 128-thr blocks, 37% occ). R8 showed occupancy
// is the dominant variable (all pipes <37% busy, latency-bound). Changes vs R5:
//  (1) weights read from GLOBAL (L1-hot 8KB table, one 64B line per (kh,kw) row)
//      -> LDS/block 22KB -> 13.7KB -> ~11 blocks/CU (22 waves) vs 6 (12 waves).
//  (2) kh-outer/lih-inner compute: live set ~70 regs = what the allocator
//      actually keeps -> emitted reads match the model (75 ds_read_b64 +
//      25 L1 loads + 450 dot2 per tap-unit) instead of blind remat.

#define XS (48*48*48)

typedef __fp16 h2 __attribute__((ext_vector_type(2)));
union UH { unsigned u; h2 h; };

__device__ __forceinline__ unsigned pk16(float a, float b) {
    UH r; r.h = __builtin_amdgcn_cvt_pkrtz(a, b);  // v_cvt_pkrtz_f16_f32
    return r.u;
}

// ---------------- Kernel 1: fold weights over C_out, pack f16 channels-last ----------------
// ws: u32[2000] = [pix 0..124][slot 0..15]; slot s = channels (2s,2s+1). ws[2000]=bias sum.
__global__ void fold_kernel(const float* __restrict__ w,
                            const float* __restrict__ bias,
                            unsigned* __restrict__ ws) {
    int t = blockIdx.x * blockDim.x + threadIdx.x;
    if (t < 2000) {
        int pix = t >> 4, sc = t & 15;
        const float* p0 = w + (size_t)(2 * sc) * 64 * 125 + pix;
        const float* p1 = p0 + 64 * 125;
        float s0 = 0.f, s1 = 0.f;
        #pragma unroll 8
        for (int o = 0; o < 64; ++o) { s0 += p0[o * 125]; s1 += p1[o * 125]; }
        ws[t] = pk16(s0, s1);
    } else if (t == 2000) {
        float s = 0.f;
        for (int o = 0; o < 64; ++o) s += bias[o];
        ((float*)ws)[2000] = s;
    }
}

// ---------------- Kernel 2: fused conv + maxpool ----------------
// Block = 128 thr = fo(5 outputs along w) x rd(6 d-window rows) x cg(4 channel quads).
// LDS: only the x tile (425 px x 8 u32 = 13.6 KB). Weights direct from global (L1).
__global__ __launch_bounds__(128)
void fused_kernel(const float* __restrict__ x,
                  const unsigned* __restrict__ wsrc,
                  float* __restrict__ out) {
    __shared__ unsigned xt[425 * 8];   // [pixel(5*5*17)][8 u32 = 16ch f16], 13.6 KB
    __shared__ float red[30];

    const int tid = threadIdx.x;
    int bid = blockIdx.x;
    const int bw = bid % 3;  bid /= 3;
    const int jh = bid % 15; bid /= 15;
    const int jd = bid % 15; const int n = bid / 15;
    const int d0 = 3 * jd - 1, h0 = 3 * jh - 1, w0 = 15 * bw - 1;

    const int fo = tid / 24;        // 0..4 (5 = idle lanes 120..127)
    const int r  = tid % 24;
    const int rd = r >> 2;          // 0..5
    const int cg = r & 3;           // channel quad within 16-ch chunk
    const bool active = tid < 120;

    const int ntd  = (rd & 1) ? 2 : 3;
    const int kd0  = rd & 1;
    const int lid0 = (rd + 4 - kd0) >> 1;

    float acc[36];
    #pragma unroll
    for (int i = 0; i < 36; ++i) acc[i] = 0.f;

    const int c2  = tid & 7;        // staging: u32 slot = channel pair (2c2, 2c2+1)
    const int p00 = tid >> 3;

    for (int chunk = 0; chunk < 2; ++chunk) {
        __syncthreads();
        // stage 16 channels as f16 pairs: xt[p][c2] (R5 pattern: proven 2.1 TB/s, 0 conflicts)
        {
            const float* xc0 = x + ((size_t)n * 32 + chunk * 16 + 2 * c2) * XS;
            const float* xc1 = xc0 + XS;
            for (int p = p00; p < 425; p += 16) {
                int dz = p / 85;
                int rm = p - dz * 85;
                int dy = rm / 17;
                int dx = rm - dy * 17;
                int gd = d0 + dz, gh = h0 + dy, gw = w0 + dx;
                unsigned v = 0;
                if (((unsigned)gd < 48u) & ((unsigned)gh < 48u) & ((unsigned)gw < 48u)) {
                    int off = (gd * 48 + gh) * 48 + gw;
                    v = pk16(xc0[off], xc1[off]);
                }
                xt[p * 8 + c2] = v;
            }
        }
        __syncthreads();

        if (active) {
            #pragma unroll
            for (int a = 0; a < 3; ++a) {
                if (a < ntd) {
                    const int lid = lid0 - a;
                    const int kd  = kd0 + 2 * a;
                    const unsigned* xb = &xt[(lid * 85 + 3 * fo) * 8 + cg * 2];
                    const unsigned* wq = wsrc + kd * 400 + chunk * 8 + cg * 2;

                    // kh-outer: load one 5-tap weight row (global, L1-hot),
                    // then its 3 valid lih rows (5 ds_read_b64 each) -> 30 dot2.
                    #pragma unroll
                    for (int kh = 0; kh < 5; ++kh) {
                        uint2 wrow[5];
                        #pragma unroll
                        for (int kw = 0; kw < 5; ++kw)
                            wrow[kw] = *(const uint2*)&wq[(kh * 5 + kw) * 16];
                        #pragma unroll
                        for (int lih = 0; lih < 5; ++lih) {
                            const int rh = 2 * lih + kh - 4;
                            if (rh >= 0 && rh < 6) {
                                uint2 irow[5];
                                #pragma unroll
                                for (int iw = 0; iw < 5; ++iw)
                                    irow[iw] = *(const uint2*)&xb[(lih * 17 + iw) * 8];
                                #pragma unroll
                                for (int liw = 0; liw < 5; ++liw) {
                                    #pragma unroll
                                    for (int kw = 0; kw < 5; ++kw) {
                                        const int rw = 2 * liw + kw - 4;
                                        if (rw >= 0 && rw < 6) {
                                            UH x0, x1, w0v, w1v;
                                            x0.u = irow[liw].x;
                                            x1.u = irow[liw].y;
                                            w0v.u = wrow[kw].x;
                                            w1v.u = wrow[kw].y;
                                            float s = acc[rh * 6 + rw];
                                            s = __builtin_amdgcn_fdot2(x0.h, w0v.h, s, false);
                                            s = __builtin_amdgcn_fdot2(x1.h, w1v.h, s, false);
                                            acc[rh * 6 + rw] = s;
                                        }
                                    }
                                }
                            }
                        }
                    }
                }
            }
        }
    }

    // sum over cg (4 adjacent lanes), then max over the 6x6 slab
    if (active) {
        #pragma unroll
        for (int i = 0; i < 36; ++i) {
            acc[i] += __shfl_xor(acc[i], 1);
            acc[i] += __shfl_xor(acc[i], 2);
        }
        if (cg == 0) {
            float m = -INFINITY;
            #pragma unroll
            for (int i = 0; i < 36; ++i) m = fmaxf(m, acc[i]);
            red[fo * 6 + rd] = m;
        }
    }
    __syncthreads();
    if (tid < 5) {
        float m = -INFINITY;
        #pragma unroll
        for (int k = 0; k < 6; ++k) m = fmaxf(m, red[tid * 6 + k]);
        float cb = ((const float*)wsrc)[2000];
        out[(((size_t)n * 15 + jd) * 15 + jh) * 15 + 5 * bw + tid] = m + cb;
    }
}

extern "C" void kernel_launch(void* const* d_in, const int* in_sizes, int n_in,
                              void* d_out, int out_size, void* d_ws, size_t ws_size,
                              hipStream_t stream) {
    const float* x = (const float*)d_in[0];
    const float* w = (const float*)d_in[1];
    const float* b = (const float*)d_in[2];
    float* out = (float*)d_out;
    unsigned* ws = (unsigned*)d_ws;

    fold_kernel<<<8, 256, 0, stream>>>(w, b, ws);

    // grid: 3 jw-groups x 15 jh x 15 jd x 16 n
    fused_kernel<<<3 * 15 * 15 * 16, 128, 0, stream>>>(x, ws, out);
}

// Round 10
// 280.813 us; speedup vs baseline: 1.3328x; 1.0167x over previous
//
#include <hip/hip_runtime.h>
#include <math.h>

// Fused ConvTranspose3d(32->64,k5,s2,p2) + sum(C_out) + bias + MaxPool(2) + MaxPool(3)
// x: (16,32,48,48,48) f32, weight: (32,64,5,5,5) f32, bias: (64,) f32
// out: (16,1,15,15,15) f32
//
// y[od] = sum x[id]*cw[kd], od = 2*id-2+kd; final out[j] = max over od in [6j,6j+5]^3 + cb.
// Window row r = 2*li + k - 4.
//
// ROUND 10 (on top of R9's 285us): counters showed dur ~= FETCH(688MB)/BW(2.2TB/s)
// -> global-staging-bound. Three fixes:
//  (1) XCD-chunked block swizzle: blocks sharing d/h-overlapped x windows land on
//      the same XCD's L2 (working set 1.47MB < 4MB) -> FETCH drops.
//  (2) Batched staging: 9 pixels per batch, 18 loads in flight before packing
//      (was load->pack->write per pixel, ~2 in flight).
//  (3) lih-outer compute: irow LDS-read once per lih (25 b64/tap-unit, was 75);
//      weight rows re-read per (lih,kh) from L1-hot global instead.

#define XS (48*48*48)

typedef __fp16 h2 __attribute__((ext_vector_type(2)));
union UH { unsigned u; h2 h; };

__device__ __forceinline__ unsigned pk16(float a, float b) {
    UH r; r.h = __builtin_amdgcn_cvt_pkrtz(a, b);  // v_cvt_pkrtz_f16_f32
    return r.u;
}

// ---------------- Kernel 1: fold weights over C_out, pack f16 channels-last ----------------
// ws: u32[2000] = [pix 0..124][slot 0..15]; slot s = channels (2s,2s+1). ws[2000]=bias sum.
__global__ void fold_kernel(const float* __restrict__ w,
                            const float* __restrict__ bias,
                            unsigned* __restrict__ ws) {
    int t = blockIdx.x * blockDim.x + threadIdx.x;
    if (t < 2000) {
        int pix = t >> 4, sc = t & 15;
        const float* p0 = w + (size_t)(2 * sc) * 64 * 125 + pix;
        const float* p1 = p0 + 64 * 125;
        float s0 = 0.f, s1 = 0.f;
        #pragma unroll 8
        for (int o = 0; o < 64; ++o) { s0 += p0[o * 125]; s1 += p1[o * 125]; }
        ws[t] = pk16(s0, s1);
    } else if (t == 2000) {
        float s = 0.f;
        for (int o = 0; o < 64; ++o) s += bias[o];
        ((float*)ws)[2000] = s;
    }
}

// ---------------- Kernel 2: fused conv + maxpool ----------------
// Block = 128 thr = fo(5 outputs along w) x rd(6 d-window rows) x cg(4 channel quads).
// LDS: only the x tile (425 px x 8 u32 = 13.6 KB). Weights direct from global (L1).
__global__ __launch_bounds__(128)
void fused_kernel(const float* __restrict__ x,
                  const unsigned* __restrict__ wsrc,
                  float* __restrict__ out) {
    __shared__ unsigned xt[425 * 8];   // [pixel(5*5*17)][8 u32 = 16ch f16], 13.6 KB
    __shared__ float red[30];

    const int tid = threadIdx.x;
    // XCD-chunked swizzle: grid 10800 = 8 x 1350. Consecutive ids round-robin
    // across XCDs; remap so each XCD gets a contiguous (bw,jh,jd,n) range ->
    // d/h-overlapping blocks share that XCD's L2.
    int bid = ((blockIdx.x & 7) * 1350) + (blockIdx.x >> 3);
    const int bw = bid % 3;  bid /= 3;
    const int jh = bid % 15; bid /= 15;
    const int jd = bid % 15; const int n = bid / 15;
    const int d0 = 3 * jd - 1, h0 = 3 * jh - 1, w0 = 15 * bw - 1;

    const int fo = tid / 24;        // 0..4 (5 = idle lanes 120..127)
    const int r  = tid % 24;
    const int rd = r >> 2;          // 0..5
    const int cg = r & 3;           // channel quad within 16-ch chunk
    const bool active = tid < 120;

    const int ntd  = (rd & 1) ? 2 : 3;
    const int kd0  = rd & 1;
    const int lid0 = (rd + 4 - kd0) >> 1;

    float acc[36];
    #pragma unroll
    for (int i = 0; i < 36; ++i) acc[i] = 0.f;

    const int c2  = tid & 7;        // staging: u32 slot = channel pair (2c2, 2c2+1)
    const int p00 = tid >> 3;

    for (int chunk = 0; chunk < 2; ++chunk) {
        __syncthreads();
        // stage 16 channels as f16 pairs: xt[p][c2]. Batched (9 px per batch):
        // issue all 18 loads, then pack+write -> ~18 loads in flight per wave.
        {
            const float* xc0 = x + ((size_t)n * 32 + chunk * 16 + 2 * c2) * XS;
            const float* xc1 = xc0 + XS;
            #pragma unroll
            for (int B = 0; B < 27; B += 9) {
                float q0[9], q1[9];
                #pragma unroll
                for (int j = 0; j < 9; ++j) {
                    int p = p00 + 16 * (B + j);
                    int dz = p / 85;
                    int rm = p - dz * 85;
                    int dy = rm / 17;
                    int dx = rm - dy * 17;
                    int gd = d0 + dz, gh = h0 + dy, gw = w0 + dx;
                    bool v = (p < 425) &
                             ((unsigned)gd < 48u) & ((unsigned)gh < 48u) & ((unsigned)gw < 48u);
                    q0[j] = 0.f; q1[j] = 0.f;
                    if (v) {
                        int off = (gd * 48 + gh) * 48 + gw;
                        q0[j] = xc0[off];
                        q1[j] = xc1[off];
                    }
                }
                #pragma unroll
                for (int j = 0; j < 9; ++j) {
                    int p = p00 + 16 * (B + j);
                    if (p < 425) xt[p * 8 + c2] = pk16(q0[j], q1[j]);
                }
            }
        }
        __syncthreads();

        if (active) {
            #pragma unroll
            for (int a = 0; a < 3; ++a) {
                if (a < ntd) {
                    const int lid = lid0 - a;
                    const int kd  = kd0 + 2 * a;
                    const unsigned* xb = &xt[(lid * 85 + 3 * fo) * 8 + cg * 2];
                    const unsigned* wq = wsrc + kd * 400 + chunk * 8 + cg * 2;

                    // lih-outer: load irow once (5 b64 LDS), then its valid kh
                    // rows (weights from L1-hot global) -> 30 dot2 each.
                    #pragma unroll
                    for (int lih = 0; lih < 5; ++lih) {
                        uint2 irow[5];
                        #pragma unroll
                        for (int iw = 0; iw < 5; ++iw)
                            irow[iw] = *(const uint2*)&xb[(lih * 17 + iw) * 8];
                        #pragma unroll
                        for (int kh = 0; kh < 5; ++kh) {
                            const int rh = 2 * lih + kh - 4;
                            if (rh >= 0 && rh < 6) {
                                uint2 wrow[5];
                                #pragma unroll
                                for (int kw = 0; kw < 5; ++kw)
                                    wrow[kw] = *(const uint2*)&wq[(kh * 5 + kw) * 16];
                                #pragma unroll
                                for (int liw = 0; liw < 5; ++liw) {
                                    #pragma unroll
                                    for (int kw = 0; kw < 5; ++kw) {
                                        const int rw = 2 * liw + kw - 4;
                                        if (rw >= 0 && rw < 6) {
                                            UH x0, x1, w0v, w1v;
                                            x0.u = irow[liw].x;
                                            x1.u = irow[liw].y;
                                            w0v.u = wrow[kw].x;
                                            w1v.u = wrow[kw].y;
                                            float s = acc[rh * 6 + rw];
                                            s = __builtin_amdgcn_fdot2(x0.h, w0v.h, s, false);
                                            s = __builtin_amdgcn_fdot2(x1.h, w1v.h, s, false);
                                            acc[rh * 6 + rw] = s;
                                        }
                                    }
                                }
                            }
                        }
                    }
                }
            }
        }
    }

    // sum over cg (4 adjacent lanes), then max over the 6x6 slab
    if (active) {
        #pragma unroll
        for (int i = 0; i < 36; ++i) {
            acc[i] += __shfl_xor(acc[i], 1);
            acc[i] += __shfl_xor(acc[i], 2);
        }
        if (cg == 0) {
            float m = -INFINITY;
            #pragma unroll
            for (int i = 0; i < 36; ++i) m = fmaxf(m, acc[i]);
            red[fo * 6 + rd] = m;
        }
    }
    __syncthreads();
    if (tid < 5) {
        float m = -INFINITY;
        #pragma unroll
        for (int k = 0; k < 6; ++k) m = fmaxf(m, red[tid * 6 + k]);
        float cb = ((const float*)wsrc)[2000];
        out[(((size_t)n * 15 + jd) * 15 + jh) * 15 + 5 * bw + tid] = m + cb;
    }
}

extern "C" void kernel_launch(void* const* d_in, const int* in_sizes, int n_in,
                              void* d_out, int out_size, void* d_ws, size_t ws_size,
                              hipStream_t stream) {
    const float* x = (const float*)d_in[0];
    const float* w = (const float*)d_in[1];
    const float* b = (const float*)d_in[2];
    float* out = (float*)d_out;
    unsigned* ws = (unsigned*)d_ws;

    fold_kernel<<<8, 256, 0, stream>>>(w, b, ws);

    // grid: 3 jw-groups x 15 jh x 15 jd x 16 n (XCD-swizzled in-kernel)
    fused_kernel<<<3 * 15 * 15 * 16, 128, 0, stream>>>(x, ws, out);
}

// Round 11
// 260.641 us; speedup vs baseline: 1.4359x; 1.0774x over previous
//
#include <hip/hip_runtime.h>
#include <math.h>

// Fused ConvTranspose3d(32->64,k5,s2,p2) + sum(C_out) + bias + MaxPool(2) + MaxPool(3)
// x: (16,32,48,48,48) f32, weight: (32,64,5,5,5) f32, bias: (64,) f32
// out: (16,1,15,15,15) f32
//
// y[od] = sum x[id]*cw[kd], od = 2*id-2+kd; final out[j] = max over od in [6j,6j+5]^3 + cb.
// Window row r = 2*li + k - 4.
//
// ROUND 11: R10 showed memory solved (FETCH 102MB, 0.34TB/s) but exec stalled
// (VALUBusy 44%, occ 22%): in-loop VMEM weight loads (L1 ~180cy) + scalar LDS
// streams. This round: zero VMEM in loop; weights cg-major in LDS so each
// thread's 25-tap block = 208 contiguous 16B-aligned bytes = 13 ds_read_b128
// loaded ONCE per (chunk,kd); x cg-major so irow = 5 contiguous b64 per lih.
// 38 LDS loads + 450 dot2 per tap-unit. Keep XCD swizzle + lean staging.

#define XS (48*48*48)

typedef __fp16 h2 __attribute__((ext_vector_type(2)));
union UH { unsigned u; h2 h; };

__device__ __forceinline__ unsigned pk16(float a, float b) {
    UH r; r.h = __builtin_amdgcn_cvt_pkrtz(a, b);  // v_cvt_pkrtz_f16_f32
    return r.u;
}

// ---------------- Kernel 1: fold weights over C_out, pack f16 cg-major ----------------
// ws layout (u32): [kd 0..4][chunk 0..1][cg 0..3][26 pairs], pair = 2ch f16.
//   slot (kd,chunk,cg)*52 + (kh*5+kw)*2 + sub   (sub: pair within quad)
//   pads [50,51] per block zeroed. ws[2080] (as float) = bias sum.
__global__ void fold_kernel(const float* __restrict__ w,
                            const float* __restrict__ bias,
                            unsigned* __restrict__ ws) {
    int t = blockIdx.x * blockDim.x + threadIdx.x;
    if (t < 2000) {
        int pix = t >> 4, sc = t & 15;
        int kd = pix / 25, r25 = pix % 25;
        int kh = r25 / 5,  kw = r25 % 5;
        int chunk = sc >> 3, lc = sc & 7;
        int cg = lc >> 1,    sub = lc & 1;
        const float* p0 = w + (size_t)(2 * sc) * 64 * 125 + pix;
        const float* p1 = p0 + 64 * 125;
        float s0 = 0.f, s1 = 0.f;
        #pragma unroll 8
        for (int o = 0; o < 64; ++o) { s0 += p0[o * 125]; s1 += p1[o * 125]; }
        ws[(((kd * 2 + chunk) * 4 + cg) * 52) + (kh * 5 + kw) * 2 + sub] = pk16(s0, s1);
    } else if (t < 2080) {
        int i = t - 2000;               // zero the 2-u32 pad per 52-u32 block
        ws[(i >> 1) * 52 + 50 + (i & 1)] = 0;
    } else if (t == 2080) {
        float s = 0.f;
        for (int o = 0; o < 64; ++o) s += bias[o];
        ((float*)ws)[2080] = s;
    }
}

// ---------------- Kernel 2: fused conv + maxpool ----------------
// Block = 128 thr = fo(5 outputs along w) x rd(6 d-window rows) x cg(4 channel quads).
// LDS: xt cg-major [cg][425 px][2 u32] (13.6 KB) + weights [40 blk][52 u32] (8.3 KB).
__global__ __launch_bounds__(128)
void fused_kernel(const float* __restrict__ x,
                  const unsigned* __restrict__ wsrc,
                  float* __restrict__ out) {
    __shared__ unsigned xt[4 * 425 * 2];   // 3400 u32 = 13.6 KB
    __shared__ unsigned cwS[2080];         // 8.32 KB
    __shared__ float red[30];

    const int tid = threadIdx.x;
    // XCD-chunked swizzle: grid 10800 = 8 x 1350 (keeps overlapped blocks on one XCD L2)
    int bid = ((blockIdx.x & 7) * 1350) + (blockIdx.x >> 3);
    const int bw = bid % 3;  bid /= 3;
    const int jh = bid % 15; bid /= 15;
    const int jd = bid % 15; const int n = bid / 15;
    const int d0 = 3 * jd - 1, h0 = 3 * jh - 1, w0 = 15 * bw - 1;

    // stage packed weights (520 x b128)
    for (int e = tid; e < 520; e += 128)
        ((uint4*)cwS)[e] = ((const uint4*)wsrc)[e];

    const int fo = tid / 24;        // 0..4 (idle lanes 120..127)
    const int r  = tid % 24;
    const int rd = r >> 2;          // 0..5
    const int cg = r & 3;           // channel quad within 16-ch chunk
    const bool active = tid < 120;

    const int ntd  = (rd & 1) ? 2 : 3;
    const int kd0  = rd & 1;
    const int lid0 = (rd + 4 - kd0) >> 1;

    float acc[36];
    #pragma unroll
    for (int i = 0; i < 36; ++i) acc[i] = 0.f;

    const int c2  = tid & 7;        // staging: channel pair (2c2, 2c2+1)
    const int p00 = tid >> 3;
    const int wgrp = c2 >> 1, wsub = c2 & 1;

    for (int chunk = 0; chunk < 2; ++chunk) {
        __syncthreads();
        // stage 16 channels as f16 pairs into cg-major xt
        {
            const float* xc0 = x + ((size_t)n * 32 + chunk * 16 + 2 * c2) * XS;
            const float* xc1 = xc0 + XS;
            for (int p = p00; p < 425; p += 16) {
                int dz = p / 85;
                int rm = p - dz * 85;
                int dy = rm / 17;
                int dx = rm - dy * 17;
                int gd = d0 + dz, gh = h0 + dy, gw = w0 + dx;
                unsigned v = 0;
                if (((unsigned)gd < 48u) & ((unsigned)gh < 48u) & ((unsigned)gw < 48u)) {
                    int off = (gd * 48 + gh) * 48 + gw;
                    v = pk16(xc0[off], xc1[off]);
                }
                xt[wgrp * 850 + p * 2 + wsub] = v;
            }
        }
        __syncthreads();

        if (active) {
            #pragma unroll
            for (int a = 0; a < 3; ++a) {
                if (a < ntd) {
                    const int lid = lid0 - a;
                    const int kd  = kd0 + 2 * a;

                    // weights for (kd, chunk, cg): 13 x b128 -> registers, once
                    union { uint4 q[13]; uint2 d[26]; } W;
                    {
                        const uint4* wb = (const uint4*)&cwS[((kd * 2 + chunk) * 4 + cg) * 52];
                        #pragma unroll
                        for (int i = 0; i < 13; ++i) W.q[i] = wb[i];
                    }

                    const unsigned* xb = &xt[cg * 850 + (lid * 85 + 3 * fo) * 2];

                    #pragma unroll
                    for (int lih = 0; lih < 5; ++lih) {
                        uint2 ir[5];
                        #pragma unroll
                        for (int iw = 0; iw < 5; ++iw)
                            ir[iw] = *(const uint2*)&xb[(lih * 17 + iw) * 2];
                        #pragma unroll
                        for (int kh = 0; kh < 5; ++kh) {
                            const int rh = 2 * lih + kh - 4;
                            if (rh >= 0 && rh < 6) {
                                #pragma unroll
                                for (int liw = 0; liw < 5; ++liw) {
                                    #pragma unroll
                                    for (int kw = 0; kw < 5; ++kw) {
                                        const int rw = 2 * liw + kw - 4;
                                        if (rw >= 0 && rw < 6) {
                                            UH x0, x1, w0v, w1v;
                                            x0.u = ir[liw].x;
                                            x1.u = ir[liw].y;
                                            w0v.u = W.d[kh * 5 + kw].x;
                                            w1v.u = W.d[kh * 5 + kw].y;
                                            float s = acc[rh * 6 + rw];
                                            s = __builtin_amdgcn_fdot2(x0.h, w0v.h, s, false);
                                            s = __builtin_amdgcn_fdot2(x1.h, w1v.h, s, false);
                                            acc[rh * 6 + rw] = s;
                                        }
                                    }
                                }
                            }
                        }
                    }
                }
            }
        }
    }

    // sum over cg (4 adjacent lanes), then max over the 6x6 slab
    if (active) {
        #pragma unroll
        for (int i = 0; i < 36; ++i) {
            acc[i] += __shfl_xor(acc[i], 1);
            acc[i] += __shfl_xor(acc[i], 2);
        }
        if (cg == 0) {
            float m = -INFINITY;
            #pragma unroll
            for (int i = 0; i < 36; ++i) m = fmaxf(m, acc[i]);
            red[fo * 6 + rd] = m;
        }
    }
    __syncthreads();
    if (tid < 5) {
        float m = -INFINITY;
        #pragma unroll
        for (int k = 0; k < 6; ++k) m = fmaxf(m, red[tid * 6 + k]);
        float cb = ((const float*)wsrc)[2080];
        out[(((size_t)n * 15 + jd) * 15 + jh) * 15 + 5 * bw + tid] = m + cb;
    }
}

extern "C" void kernel_launch(void* const* d_in, const int* in_sizes, int n_in,
                              void* d_out, int out_size, void* d_ws, size_t ws_size,
                              hipStream_t stream) {
    const float* x = (const float*)d_in[0];
    const float* w = (const float*)d_in[1];
    const float* b = (const float*)d_in[2];
    float* out = (float*)d_out;
    unsigned* ws = (unsigned*)d_ws;

    fold_kernel<<<9, 256, 0, stream>>>(w, b, ws);

    // grid: 3 jw-groups x 15 jh x 15 jd x 16 n (XCD-swizzled in-kernel)
    fused_kernel<<<3 * 15 * 15 * 16, 128, 0, stream>>>(x, ws, out);
}

// Round 12
// 236.294 us; speedup vs baseline: 1.5839x; 1.1030x over previous
//
#include <hip/hip_runtime.h>
#include <math.h>

// Fused ConvTranspose3d(32->64,k5,s2,p2) + sum(C_out) + bias + MaxPool(2) + MaxPool(3)
// x: (16,32,48,48,48) f32, weight: (32,64,5,5,5) f32, bias: (64,) f32
// out: (16,1,15,15,15) f32
//
// y[od] = sum x[id]*cw[kd], od = 2*id-2+kd; final out[j] = max over od in [6j,6j+5]^3 + cb.
// Window row r = 2*li + k - 4.
//
// ROUND 12 (from R11's 260us): VGPR=60 showed the allocator still drops the
// weight block and re-reads LDS; rd-parity divergence wastes 1/6 of issue;
// occupancy capped at 14 waves/CU. Fixes:
//  (1) opaque asm pin on the 13 b128 weight regs -> remat impossible;
//  (2) parity-uniform waves: rd = 2*rdi + (wave&1); even waves run 3 d-taps,
//      odd waves 2 (wave-uniform branch, no masked third unit);
//  (3) 256-thr block = 2 n-paired tiles sharing the weight LDS copy
//      (35.8 KB -> 4 blocks x 4 waves = 16 waves/CU; weight refetch halved).

#define XS (48*48*48)

typedef __fp16 h2 __attribute__((ext_vector_type(2)));
union UH { unsigned u; h2 h; };

__device__ __forceinline__ unsigned pk16(float a, float b) {
    UH r; r.h = __builtin_amdgcn_cvt_pkrtz(a, b);  // v_cvt_pkrtz_f16_f32
    return r.u;
}

// ---------------- Kernel 1: fold weights over C_out, pack f16 cg-major ----------------
// ws layout (u32): [kd 0..4][chunk 0..1][cg 0..3][26 pairs]; pair = 2ch f16.
// pads [50,51] per 52-u32 block zeroed. ws[2080] (as float) = bias sum.
__global__ void fold_kernel(const float* __restrict__ w,
                            const float* __restrict__ bias,
                            unsigned* __restrict__ ws) {
    int t = blockIdx.x * blockDim.x + threadIdx.x;
    if (t < 2000) {
        int pix = t >> 4, sc = t & 15;
        int kd = pix / 25, r25 = pix % 25;
        int kh = r25 / 5,  kw = r25 % 5;
        int chunk = sc >> 3, lc = sc & 7;
        int cg = lc >> 1,    sub = lc & 1;
        const float* p0 = w + (size_t)(2 * sc) * 64 * 125 + pix;
        const float* p1 = p0 + 64 * 125;
        float s0 = 0.f, s1 = 0.f;
        #pragma unroll 8
        for (int o = 0; o < 64; ++o) { s0 += p0[o * 125]; s1 += p1[o * 125]; }
        ws[(((kd * 2 + chunk) * 4 + cg) * 52) + (kh * 5 + kw) * 2 + sub] = pk16(s0, s1);
    } else if (t < 2080) {
        int i = t - 2000;
        ws[(i >> 1) * 52 + 50 + (i & 1)] = 0;
    } else if (t == 2080) {
        float s = 0.f;
        for (int o = 0; o < 64; ++o) s += bias[o];
        ((float*)ws)[2080] = s;
    }
}

union WU { uint4 q; uint2 d[2]; unsigned u[4]; };

// ---------------- Kernel 2: fused conv + maxpool ----------------
// Block = 256 thr = 2 tiles (n-paired). Per tile: 2 waves; wave parity = rd parity.
// Lane: fo = lane/12 (0..4), rdi = (lane%12)>>2 (0..2), cg = lane&3; rd = 2*rdi+wpar.
__global__ __launch_bounds__(256)
void fused_kernel(const float* __restrict__ x,
                  const unsigned* __restrict__ wsrc,
                  float* __restrict__ out) {
    __shared__ unsigned xt[2 * 4 * 425 * 2];  // [tile][cg][425 px][2], 27.2 KB
    __shared__ unsigned cwS[2080];            // 8.32 KB (shared by both tiles)
    __shared__ float red[60];                 // [tile][fo(5)][rd(6)]

    const int tid = threadIdx.x;
    // XCD-chunked swizzle: grid 5400 = 8 x 675 (675 = full bw*jh*jd per n-pair)
    int bid = ((blockIdx.x & 7) * 675) + (blockIdx.x >> 3);
    const int bw = bid % 3;  bid /= 3;
    const int jh = bid % 15; bid /= 15;
    const int jd = bid % 15; const int nb = bid / 15;   // n-pair 0..7
    const int d0 = 3 * jd - 1, h0 = 3 * jh - 1, w0 = 15 * bw - 1;

    const int t    = tid >> 7;          // tile 0/1
    const int n    = nb * 2 + t;

    // stage packed weights once (520 x b128, whole block)
    for (int e = tid; e < 520; e += 256)
        ((uint4*)cwS)[e] = ((const uint4*)wsrc)[e];

    // compute-lane decode
    const int lane = tid & 63;
    const int wpar = (tid >> 6) & 1;    // rd parity of this wave
    const int fo   = lane / 12;         // 0..4 (lane 60..63 idle)
    const int rdi  = (lane % 12) >> 2;  // 0..2
    const int cg   = lane & 3;
    const bool active = lane < 60;
    const int rd   = 2 * rdi + wpar;
    const int ntd  = wpar ? 2 : 3;      // wave-uniform

    // staging-lane decode (per tile: 128 threads)
    const int tid2 = tid & 127;
    const int c2   = tid2 & 7;          // channel pair (2c2, 2c2+1)
    const int p00  = tid2 >> 3;         // 0..15

    float acc[36];
    #pragma unroll
    for (int i = 0; i < 36; ++i) acc[i] = 0.f;

    for (int chunk = 0; chunk < 2; ++chunk) {
        __syncthreads();
        // stage 16 channels as f16 pairs into cg-major xt (own tile's region)
        {
            const float* xc0 = x + ((size_t)n * 32 + chunk * 16 + 2 * c2) * XS;
            const float* xc1 = xc0 + XS;
            unsigned* xdst = &xt[t * 3400 + (c2 >> 1) * 850 + (c2 & 1)];
            for (int p = p00; p < 425; p += 16) {
                int dz = p / 85;
                int rm = p - dz * 85;
                int dy = rm / 17;
                int dx = rm - dy * 17;
                int gd = d0 + dz, gh = h0 + dy, gw = w0 + dx;
                unsigned v = 0;
                if (((unsigned)gd < 48u) & ((unsigned)gh < 48u) & ((unsigned)gw < 48u)) {
                    int off = (gd * 48 + gh) * 48 + gw;
                    v = pk16(xc0[off], xc1[off]);
                }
                xdst[p * 2] = v;
            }
        }
        __syncthreads();

        if (active) {
            #pragma unroll
            for (int a = 0; a < 3; ++a) {
                if (a < ntd) {                       // wave-uniform branch
                    const int lid = rdi + 2 - a;
                    const int kd  = wpar + 2 * a;

                    // weights for (kd, chunk, cg): 13 b128 -> pinned registers
                    WU W[13];
                    {
                        const uint4* wb = (const uint4*)&cwS[((kd * 2 + chunk) * 4 + cg) * 52];
                        #pragma unroll
                        for (int i = 0; i < 13; ++i) {
                            W[i].q = wb[i];
                            asm volatile("" : "+v"(W[i].q.x), "+v"(W[i].q.y),
                                              "+v"(W[i].q.z), "+v"(W[i].q.w));
                        }
                    }

                    const unsigned* xb = &xt[t * 3400 + cg * 850 + (lid * 85 + 3 * fo) * 2];

                    #pragma unroll
                    for (int lih = 0; lih < 5; ++lih) {
                        uint2 ir[5];
                        #pragma unroll
                        for (int iw = 0; iw < 5; ++iw)
                            ir[iw] = *(const uint2*)&xb[(lih * 17 + iw) * 2];
                        #pragma unroll
                        for (int kh = 0; kh < 5; ++kh) {
                            const int rh = 2 * lih + kh - 4;
                            if (rh >= 0 && rh < 6) {
                                #pragma unroll
                                for (int liw = 0; liw < 5; ++liw) {
                                    #pragma unroll
                                    for (int kw = 0; kw < 5; ++kw) {
                                        const int rw = 2 * liw + kw - 4;
                                        if (rw >= 0 && rw < 6) {
                                            const int j2 = (kh * 5 + kw) * 2;
                                            UH x0, x1, w0v, w1v;
                                            x0.u  = ir[liw].x;
                                            x1.u  = ir[liw].y;
                                            w0v.u = W[j2 >> 2].u[j2 & 3];
                                            w1v.u = W[(j2 + 1) >> 2].u[(j2 + 1) & 3];
                                            float s = acc[rh * 6 + rw];
                                            s = __builtin_amdgcn_fdot2(x0.h, w0v.h, s, false);
                                            s = __builtin_amdgcn_fdot2(x1.h, w1v.h, s, false);
                                            acc[rh * 6 + rw] = s;
                                        }
                                    }
                                }
                            }
                        }
                    }
                }
            }
        }
    }

    // sum over cg (4 adjacent lanes), then max over the 6x6 slab
    if (active) {
        #pragma unroll
        for (int i = 0; i < 36; ++i) {
            acc[i] += __shfl_xor(acc[i], 1);
            acc[i] += __shfl_xor(acc[i], 2);
        }
        if (cg == 0) {
            float m = -INFINITY;
            #pragma unroll
            for (int i = 0; i < 36; ++i) m = fmaxf(m, acc[i]);
            red[t * 30 + fo * 6 + rd] = m;
        }
    }
    __syncthreads();
    if (tid < 10) {
        const int tt = tid / 5, ff = tid % 5;
        float m = -INFINITY;
        #pragma unroll
        for (int k = 0; k < 6; ++k) m = fmaxf(m, red[tt * 30 + ff * 6 + k]);
        float cb = ((const float*)wsrc)[2080];
        out[(((size_t)(nb * 2 + tt) * 15 + jd) * 15 + jh) * 15 + 5 * bw + ff] = m + cb;
    }
}

extern "C" void kernel_launch(void* const* d_in, const int* in_sizes, int n_in,
                              void* d_out, int out_size, void* d_ws, size_t ws_size,
                              hipStream_t stream) {
    const float* x = (const float*)d_in[0];
    const float* w = (const float*)d_in[1];
    const float* b = (const float*)d_in[2];
    float* out = (float*)d_out;
    unsigned* ws = (unsigned*)d_ws;

    fold_kernel<<<9, 256, 0, stream>>>(w, b, ws);

    // grid: 3 bw x 15 jh x 15 jd x 8 n-pairs (XCD-swizzled in-kernel)
    fused_kernel<<<3 * 15 * 15 * 8, 256, 0, stream>>>(x, ws, out);
}

// Round 13
// 234.279 us; speedup vs baseline: 1.5975x; 1.0086x over previous
//
#include <hip/hip_runtime.h>
#include <math.h>

// Fused ConvTranspose3d(32->64,k5,s2,p2) + sum(C_out) + bias + MaxPool(2) + MaxPool(3)
// x: (16,32,48,48,48) f32, weight: (32,64,5,5,5) f32, bias: (64,) f32
// out: (16,1,15,15,15) f32
//
// y[od] = sum x[id]*cw[kd], od = 2*id-2+kd; final out[j] = max over od in [6j,6j+5]^3 + cb.
// Window row r = 2*li + k - 4.
//
// ROUND 13 (single-variable experiment on R12's 236us): R12 reported VGPR=64 --
// the allocator sits on the 64-reg occupancy cliff even though LDS (35.8KB ->
// 4 blocks x 4 waves) already caps the CU at 16 waves, which VGPR<=128 supports
// equally. At 64 regs the 13x-b128 weight block cannot stay resident (acc 36 +
// W 52 > 64) so it re-reads LDS every use (20.6M bank-conflict cycles, ~4x VALU
// bloat). __launch_bounds__(256, 4) = min 4 waves/EU = 16 waves/CU -> VGPR cap
// 128: live set (~113) fits, no occupancy loss, W block finally sticks.

#define XS (48*48*48)

typedef __fp16 h2 __attribute__((ext_vector_type(2)));
union UH { unsigned u; h2 h; };

__device__ __forceinline__ unsigned pk16(float a, float b) {
    UH r; r.h = __builtin_amdgcn_cvt_pkrtz(a, b);  // v_cvt_pkrtz_f16_f32
    return r.u;
}

// ---------------- Kernel 1: fold weights over C_out, pack f16 cg-major ----------------
// ws layout (u32): [kd 0..4][chunk 0..1][cg 0..3][26 pairs]; pair = 2ch f16.
// pads [50,51] per 52-u32 block zeroed. ws[2080] (as float) = bias sum.
__global__ void fold_kernel(const float* __restrict__ w,
                            const float* __restrict__ bias,
                            unsigned* __restrict__ ws) {
    int t = blockIdx.x * blockDim.x + threadIdx.x;
    if (t < 2000) {
        int pix = t >> 4, sc = t & 15;
        int kd = pix / 25, r25 = pix % 25;
        int kh = r25 / 5,  kw = r25 % 5;
        int chunk = sc >> 3, lc = sc & 7;
        int cg = lc >> 1,    sub = lc & 1;
        const float* p0 = w + (size_t)(2 * sc) * 64 * 125 + pix;
        const float* p1 = p0 + 64 * 125;
        float s0 = 0.f, s1 = 0.f;
        #pragma unroll 8
        for (int o = 0; o < 64; ++o) { s0 += p0[o * 125]; s1 += p1[o * 125]; }
        ws[(((kd * 2 + chunk) * 4 + cg) * 52) + (kh * 5 + kw) * 2 + sub] = pk16(s0, s1);
    } else if (t < 2080) {
        int i = t - 2000;
        ws[(i >> 1) * 52 + 50 + (i & 1)] = 0;
    } else if (t == 2080) {
        float s = 0.f;
        for (int o = 0; o < 64; ++o) s += bias[o];
        ((float*)ws)[2080] = s;
    }
}

union WU { uint4 q; uint2 d[2]; unsigned u[4]; };

// ---------------- Kernel 2: fused conv + maxpool ----------------
// Block = 256 thr = 2 tiles (n-paired). Per tile: 2 waves; wave parity = rd parity.
// Lane: fo = lane/12 (0..4), rdi = (lane%12)>>2 (0..2), cg = lane&3; rd = 2*rdi+wpar.
__global__ __launch_bounds__(256, 4)
void fused_kernel(const float* __restrict__ x,
                  const unsigned* __restrict__ wsrc,
                  float* __restrict__ out) {
    __shared__ unsigned xt[2 * 4 * 425 * 2];  // [tile][cg][425 px][2], 27.2 KB
    __shared__ unsigned cwS[2080];            // 8.32 KB (shared by both tiles)
    __shared__ float red[60];                 // [tile][fo(5)][rd(6)]

    const int tid = threadIdx.x;
    // XCD-chunked swizzle: grid 5400 = 8 x 675 (675 = full bw*jh*jd per n-pair)
    int bid = ((blockIdx.x & 7) * 675) + (blockIdx.x >> 3);
    const int bw = bid % 3;  bid /= 3;
    const int jh = bid % 15; bid /= 15;
    const int jd = bid % 15; const int nb = bid / 15;   // n-pair 0..7
    const int d0 = 3 * jd - 1, h0 = 3 * jh - 1, w0 = 15 * bw - 1;

    const int t    = tid >> 7;          // tile 0/1
    const int n    = nb * 2 + t;

    // stage packed weights once (520 x b128, whole block)
    for (int e = tid; e < 520; e += 256)
        ((uint4*)cwS)[e] = ((const uint4*)wsrc)[e];

    // compute-lane decode
    const int lane = tid & 63;
    const int wpar = (tid >> 6) & 1;    // rd parity of this wave
    const int fo   = lane / 12;         // 0..4 (lane 60..63 idle)
    const int rdi  = (lane % 12) >> 2;  // 0..2
    const int cg   = lane & 3;
    const bool active = lane < 60;
    const int rd   = 2 * rdi + wpar;
    const int ntd  = wpar ? 2 : 3;      // wave-uniform

    // staging-lane decode (per tile: 128 threads)
    const int tid2 = tid & 127;
    const int c2   = tid2 & 7;          // channel pair (2c2, 2c2+1)
    const int p00  = tid2 >> 3;         // 0..15

    float acc[36];
    #pragma unroll
    for (int i = 0; i < 36; ++i) acc[i] = 0.f;

    for (int chunk = 0; chunk < 2; ++chunk) {
        __syncthreads();
        // stage 16 channels as f16 pairs into cg-major xt (own tile's region)
        {
            const float* xc0 = x + ((size_t)n * 32 + chunk * 16 + 2 * c2) * XS;
            const float* xc1 = xc0 + XS;
            unsigned* xdst = &xt[t * 3400 + (c2 >> 1) * 850 + (c2 & 1)];
            for (int p = p00; p < 425; p += 16) {
                int dz = p / 85;
                int rm = p - dz * 85;
                int dy = rm / 17;
                int dx = rm - dy * 17;
                int gd = d0 + dz, gh = h0 + dy, gw = w0 + dx;
                unsigned v = 0;
                if (((unsigned)gd < 48u) & ((unsigned)gh < 48u) & ((unsigned)gw < 48u)) {
                    int off = (gd * 48 + gh) * 48 + gw;
                    v = pk16(xc0[off], xc1[off]);
                }
                xdst[p * 2] = v;
            }
        }
        __syncthreads();

        if (active) {
            #pragma unroll
            for (int a = 0; a < 3; ++a) {
                if (a < ntd) {                       // wave-uniform branch
                    const int lid = rdi + 2 - a;
                    const int kd  = wpar + 2 * a;

                    // weights for (kd, chunk, cg): 13 b128 -> pinned registers
                    WU W[13];
                    {
                        const uint4* wb = (const uint4*)&cwS[((kd * 2 + chunk) * 4 + cg) * 52];
                        #pragma unroll
                        for (int i = 0; i < 13; ++i) {
                            W[i].q = wb[i];
                            asm volatile("" : "+v"(W[i].q.x), "+v"(W[i].q.y),
                                              "+v"(W[i].q.z), "+v"(W[i].q.w));
                        }
                    }

                    const unsigned* xb = &xt[t * 3400 + cg * 850 + (lid * 85 + 3 * fo) * 2];

                    #pragma unroll
                    for (int lih = 0; lih < 5; ++lih) {
                        uint2 ir[5];
                        #pragma unroll
                        for (int iw = 0; iw < 5; ++iw)
                            ir[iw] = *(const uint2*)&xb[(lih * 17 + iw) * 2];
                        #pragma unroll
                        for (int kh = 0; kh < 5; ++kh) {
                            const int rh = 2 * lih + kh - 4;
                            if (rh >= 0 && rh < 6) {
                                #pragma unroll
                                for (int liw = 0; liw < 5; ++liw) {
                                    #pragma unroll
                                    for (int kw = 0; kw < 5; ++kw) {
                                        const int rw = 2 * liw + kw - 4;
                                        if (rw >= 0 && rw < 6) {
                                            const int j2 = (kh * 5 + kw) * 2;
                                            UH x0, x1, w0v, w1v;
                                            x0.u  = ir[liw].x;
                                            x1.u  = ir[liw].y;
                                            w0v.u = W[j2 >> 2].u[j2 & 3];
                                            w1v.u = W[(j2 + 1) >> 2].u[(j2 + 1) & 3];
                                            float s = acc[rh * 6 + rw];
                                            s = __builtin_amdgcn_fdot2(x0.h, w0v.h, s, false);
                                            s = __builtin_amdgcn_fdot2(x1.h, w1v.h, s, false);
                                            acc[rh * 6 + rw] = s;
                                        }
                                    }
                                }
                            }
                        }
                    }
                }
            }
        }
    }

    // sum over cg (4 adjacent lanes), then max over the 6x6 slab
    if (active) {
        #pragma unroll
        for (int i = 0; i < 36; ++i) {
            acc[i] += __shfl_xor(acc[i], 1);
            acc[i] += __shfl_xor(acc[i], 2);
        }
        if (cg == 0) {
            float m = -INFINITY;
            #pragma unroll
            for (int i = 0; i < 36; ++i) m = fmaxf(m, acc[i]);
            red[t * 30 + fo * 6 + rd] = m;
        }
    }
    __syncthreads();
    if (tid < 10) {
        const int tt = tid / 5, ff = tid % 5;
        float m = -INFINITY;
        #pragma unroll
        for (int k = 0; k < 6; ++k) m = fmaxf(m, red[tt * 30 + ff * 6 + k]);
        float cb = ((const float*)wsrc)[2080];
        out[(((size_t)(nb * 2 + tt) * 15 + jd) * 15 + jh) * 15 + 5 * bw + ff] = m + cb;
    }
}

extern "C" void kernel_launch(void* const* d_in, const int* in_sizes, int n_in,
                              void* d_out, int out_size, void* d_ws, size_t ws_size,
                              hipStream_t stream) {
    const float* x = (const float*)d_in[0];
    const float* w = (const float*)d_in[1];
    const float* b = (const float*)d_in[2];
    float* out = (float*)d_out;
    unsigned* ws = (unsigned*)d_ws;

    fold_kernel<<<9, 256, 0, stream>>>(w, b, ws);

    // grid: 3 bw x 15 jh x 15 jd x 8 n-pairs (XCD-swizzled in-kernel)
    fused_kernel<<<3 * 15 * 15 * 8, 256, 0, stream>>>(x, ws, out);
}

// Round 14
// 227.500 us; speedup vs baseline: 1.6451x; 1.0298x over previous
//
#include <hip/hip_runtime.h>
#include <math.h>

// Fused ConvTranspose3d(32->64,k5,s2,p2) + sum(C_out) + bias + MaxPool(2) + MaxPool(3)
// x: (16,32,48,48,48) f32, weight: (32,64,5,5,5) f32, bias: (64,) f32
// out: (16,1,15,15,15) f32
//
// y[od] = sum x[id]*cw[kd], od = 2*id-2+kd; final out[j] = max over od in [6j,6j+5]^3 + cb.
// Window row r = 2*li + k - 4.
//
// ROUND 14: R13 falsified the "VGPR cap" theory (launch_bounds(256,4) -> still 64).
// Issue audit: VALUBusy*dur => ~8700 VALU insts/thread vs ~3200 modeled => ~2 extra
// VALU per dot2 emitted by the compiler's 64-reg schedule. Fix: emit each tap pair
// as a non-volatile inline-asm block of exactly 2x v_dot2_f32_f16 (acc "+v");
// compiler still schedules/allocates but cannot bloat the inner loop. Also revert
// xt to pixel-major (R5's 0-conflict layout; R11's cg-major caused 20.6M conflict
// cycles) and plain launch_bounds(256). Parity waves + n-pairing + XCD swizzle kept.

#define XS (48*48*48)

typedef __fp16 h2 __attribute__((ext_vector_type(2)));
union UH { unsigned u; h2 h; };

__device__ __forceinline__ unsigned pk16(float a, float b) {
    UH r; r.h = __builtin_amdgcn_cvt_pkrtz(a, b);  // v_cvt_pkrtz_f16_f32
    return r.u;
}

// exactly two v_dot2_f32_f16: acc += dot(ir.x, w0) + dot(ir.y, w1)
#define DOT2PAIR(ACC, IR, W0, W1)                                        \
    asm("v_dot2_f32_f16 %0, %1, %3, %0\n\t"                              \
        "v_dot2_f32_f16 %0, %2, %4, %0"                                  \
        : "+v"(ACC)                                                      \
        : "v"(IR.x), "v"(IR.y), "v"(W0), "v"(W1))

// ---------------- Kernel 1: fold weights over C_out, pack f16 cg-major ----------------
// ws layout (u32): [kd 0..4][chunk 0..1][cg 0..3][26 pairs]; pair = 2ch f16.
// pads [50,51] per 52-u32 block zeroed. ws[2080] (as float) = bias sum.
__global__ void fold_kernel(const float* __restrict__ w,
                            const float* __restrict__ bias,
                            unsigned* __restrict__ ws) {
    int t = blockIdx.x * blockDim.x + threadIdx.x;
    if (t < 2000) {
        int pix = t >> 4, sc = t & 15;
        int kd = pix / 25, r25 = pix % 25;
        int kh = r25 / 5,  kw = r25 % 5;
        int chunk = sc >> 3, lc = sc & 7;
        int cg = lc >> 1,    sub = lc & 1;
        const float* p0 = w + (size_t)(2 * sc) * 64 * 125 + pix;
        const float* p1 = p0 + 64 * 125;
        float s0 = 0.f, s1 = 0.f;
        #pragma unroll 8
        for (int o = 0; o < 64; ++o) { s0 += p0[o * 125]; s1 += p1[o * 125]; }
        ws[(((kd * 2 + chunk) * 4 + cg) * 52) + (kh * 5 + kw) * 2 + sub] = pk16(s0, s1);
    } else if (t < 2080) {
        int i = t - 2000;
        ws[(i >> 1) * 52 + 50 + (i & 1)] = 0;
    } else if (t == 2080) {
        float s = 0.f;
        for (int o = 0; o < 64; ++o) s += bias[o];
        ((float*)ws)[2080] = s;
    }
}

union WU { uint4 q; uint2 d[2]; unsigned u[4]; };

// ---------------- Kernel 2: fused conv + maxpool ----------------
// Block = 256 thr = 2 tiles (n-paired). Per tile: 2 waves; wave parity = rd parity.
// Lane: fo = lane/12 (0..4), rdi = (lane%12)>>2 (0..2), cg = lane&3; rd = 2*rdi+wpar.
// xt pixel-major: [tile][425 px][8 u32 = 16ch f16 pairs].
__global__ __launch_bounds__(256)
void fused_kernel(const float* __restrict__ x,
                  const unsigned* __restrict__ wsrc,
                  float* __restrict__ out) {
    __shared__ unsigned xt[2 * 425 * 8];      // 27.2 KB
    __shared__ unsigned cwS[2080];            // 8.32 KB (shared by both tiles)
    __shared__ float red[60];                 // [tile][fo(5)][rd(6)]

    const int tid = threadIdx.x;
    // XCD-chunked swizzle: grid 5400 = 8 x 675 (675 = full bw*jh*jd per n-pair)
    int bid = ((blockIdx.x & 7) * 675) + (blockIdx.x >> 3);
    const int bw = bid % 3;  bid /= 3;
    const int jh = bid % 15; bid /= 15;
    const int jd = bid % 15; const int nb = bid / 15;   // n-pair 0..7
    const int d0 = 3 * jd - 1, h0 = 3 * jh - 1, w0 = 15 * bw - 1;

    const int t    = tid >> 7;          // tile 0/1
    const int n    = nb * 2 + t;

    // stage packed weights once (520 x b128, whole block)
    for (int e = tid; e < 520; e += 256)
        ((uint4*)cwS)[e] = ((const uint4*)wsrc)[e];

    // compute-lane decode
    const int lane = tid & 63;
    const int wpar = (tid >> 6) & 1;    // rd parity of this wave
    const int fo   = lane / 12;         // 0..4 (lane 60..63 idle)
    const int rdi  = (lane % 12) >> 2;  // 0..2
    const int cg   = lane & 3;
    const bool active = lane < 60;
    const int rd   = 2 * rdi + wpar;
    const int ntd  = wpar ? 2 : 3;      // wave-uniform

    // staging-lane decode (per tile: 128 threads)
    const int tid2 = tid & 127;
    const int c2   = tid2 & 7;          // channel pair (2c2, 2c2+1)
    const int p00  = tid2 >> 3;         // 0..15

    float acc[36];
    #pragma unroll
    for (int i = 0; i < 36; ++i) acc[i] = 0.f;

    for (int chunk = 0; chunk < 2; ++chunk) {
        __syncthreads();
        // stage 16 channels as f16 pairs, pixel-major (write addr == lane: conflict-free)
        {
            const float* xc0 = x + ((size_t)n * 32 + chunk * 16 + 2 * c2) * XS;
            const float* xc1 = xc0 + XS;
            unsigned* xdst = &xt[t * 3400 + c2];
            for (int p = p00; p < 425; p += 16) {
                int dz = p / 85;
                int rm = p - dz * 85;
                int dy = rm / 17;
                int dx = rm - dy * 17;
                int gd = d0 + dz, gh = h0 + dy, gw = w0 + dx;
                unsigned v = 0;
                if (((unsigned)gd < 48u) & ((unsigned)gh < 48u) & ((unsigned)gw < 48u)) {
                    int off = (gd * 48 + gh) * 48 + gw;
                    v = pk16(xc0[off], xc1[off]);
                }
                xdst[p * 8] = v;
            }
        }
        __syncthreads();

        if (active) {
            #pragma unroll
            for (int a = 0; a < 3; ++a) {
                if (a < ntd) {                       // wave-uniform branch
                    const int lid = rdi + 2 - a;
                    const int kd  = wpar + 2 * a;

                    // weights for (kd, chunk, cg): 13 x b128 (broadcast within cg group)
                    WU W[13];
                    {
                        const uint4* wb = (const uint4*)&cwS[((kd * 2 + chunk) * 4 + cg) * 52];
                        #pragma unroll
                        for (int i = 0; i < 13; ++i) W[i].q = wb[i];
                    }

                    const unsigned* xb = &xt[t * 3400 + (lid * 85 + 3 * fo) * 8 + cg * 2];

                    #pragma unroll
                    for (int lih = 0; lih < 5; ++lih) {
                        uint2 ir[5];
                        #pragma unroll
                        for (int iw = 0; iw < 5; ++iw)
                            ir[iw] = *(const uint2*)&xb[(lih * 17 + iw) * 8];
                        #pragma unroll
                        for (int kh = 0; kh < 5; ++kh) {
                            const int rh = 2 * lih + kh - 4;
                            if (rh >= 0 && rh < 6) {
                                #pragma unroll
                                for (int liw = 0; liw < 5; ++liw) {
                                    #pragma unroll
                                    for (int kw = 0; kw < 5; ++kw) {
                                        const int rw = 2 * liw + kw - 4;
                                        if (rw >= 0 && rw < 6) {
                                            const int j2 = (kh * 5 + kw) * 2;
                                            DOT2PAIR(acc[rh * 6 + rw], ir[liw],
                                                     W[j2 >> 2].u[j2 & 3],
                                                     W[(j2 + 1) >> 2].u[(j2 + 1) & 3]);
                                        }
                                    }
                                }
                            }
                        }
                    }
                }
            }
        }
    }

    // sum over cg (4 adjacent lanes), then max over the 6x6 slab
    if (active) {
        #pragma unroll
        for (int i = 0; i < 36; ++i) {
            acc[i] += __shfl_xor(acc[i], 1);
            acc[i] += __shfl_xor(acc[i], 2);
        }
        if (cg == 0) {
            float m = -INFINITY;
            #pragma unroll
            for (int i = 0; i < 36; ++i) m = fmaxf(m, acc[i]);
            red[t * 30 + fo * 6 + rd] = m;
        }
    }
    __syncthreads();
    if (tid < 10) {
        const int tt = tid / 5, ff = tid % 5;
        float m = -INFINITY;
        #pragma unroll
        for (int k = 0; k < 6; ++k) m = fmaxf(m, red[tt * 30 + ff * 6 + k]);
        float cb = ((const float*)wsrc)[2080];
        out[(((size_t)(nb * 2 + tt) * 15 + jd) * 15 + jh) * 15 + 5 * bw + ff] = m + cb;
    }
}

extern "C" void kernel_launch(void* const* d_in, const int* in_sizes, int n_in,
                              void* d_out, int out_size, void* d_ws, size_t ws_size,
                              hipStream_t stream) {
    const float* x = (const float*)d_in[0];
    const float* w = (const float*)d_in[1];
    const float* b = (const float*)d_in[2];
    float* out = (float*)d_out;
    unsigned* ws = (unsigned*)d_ws;

    fold_kernel<<<9, 256, 0, stream>>>(w, b, ws);

    // grid: 3 bw x 15 jh x 15 jd x 8 n-pairs (XCD-swizzled in-kernel)
    fused_kernel<<<3 * 15 * 15 * 8, 256, 0, stream>>>(x, ws, out);
}